// Round 4
// baseline (698.316 us; speedup 1.0000x reference)
//
#include <hip/hip_runtime.h>
#include <hip/hip_bf16.h>

#define B_DIM 128
#define S_DIM 512
#define D_DIM 1024
#define GEN_VV 50000
#define OUT_VV 50257
#define LDK 72   // LDS row stride (bf16 elems): 144 B, keeps b128 16B-aligned, bank-uniform

typedef float f32x4 __attribute__((ext_vector_type(4)));
typedef __bf16 bf16x8 __attribute__((ext_vector_type(8)));
typedef __bf16 bf16x4 __attribute__((ext_vector_type(4)));
typedef __bf16 bf16x2 __attribute__((ext_vector_type(2)));

// ---------------- K1: gate + x -> bf16 ----------------
__global__ __launch_bounds__(256) void k_gate(const float* __restrict__ x,
        const float* __restrict__ Wg, const float* __restrict__ bgate,
        __bf16* __restrict__ xb, float* __restrict__ interp) {
    __shared__ float red[4];
    const int b = blockIdx.x, t = threadIdx.x;
    float4 xv = reinterpret_cast<const float4*>(x + (size_t)b * D_DIM)[t];
    float4 wv = reinterpret_cast<const float4*>(Wg)[t];
    float dot = xv.x * wv.x + xv.y * wv.y + xv.z * wv.z + xv.w * wv.w;
    bf16x4 hb;
    hb[0] = (__bf16)xv.x; hb[1] = (__bf16)xv.y; hb[2] = (__bf16)xv.z; hb[3] = (__bf16)xv.w;
    reinterpret_cast<bf16x4*>(xb + (size_t)b * D_DIM)[t] = hb;
#pragma unroll
    for (int m = 32; m >= 1; m >>= 1) dot += __shfl_xor(dot, m);
    if ((t & 63) == 0) red[t >> 6] = dot;
    __syncthreads();
    if (t == 0) {
        float d = red[0] + red[1] + red[2] + red[3] + bgate[0];
        interp[b] = 1.0f / (1.0f + __expf(-d));
    }
}

// ---------------- K2: GEMM logits = x @ W_gen + b_gen ----------------
// BM=128, BN=64, BK=64, 256 thr (4 waves, 2x2), slot-major LDS so each
// MFMA fragment is one ds_read_b128. A,B share the same k->slot bijection:
// within a 32-k slice, pos = ((k&15)>>2)*8 + (k&3) + 4*((k&31)>>4).
__global__ __launch_bounds__(256) void k_gemm(const __bf16* __restrict__ xb,
        const float* __restrict__ W, const float* __restrict__ bgen,
        float* __restrict__ logits) {
    __shared__ __align__(16) __bf16 As[128 * LDK];  // 18,432 B
    __shared__ __align__(16) __bf16 Ws[64 * LDK];   //  9,216 B
    const int t = threadIdx.x;
    const int lane = t & 63, wv = t >> 6;
    const int wr = wv >> 1, wc = wv & 1;
    const int g = lane >> 4, r16 = lane & 15;
    const int nb = blockIdx.x * 64;

    // W staging map: thread -> (kl = 2*(t&15) [+32], nn = (t>>4)*4)
    const int uk = t & 15, qn = t >> 4;
    const int kk = uk * 2, nn = qn * 4;
    const bool wval = (nb + nn + 3) < GEN_VV;
    const int pos0 = ((kk & 15) >> 2) * 8 + (kk & 3) + 4 * (kk >> 4);  // slice 0
    const int pos1 = 32 + pos0;                                        // slice 1 (kl=kk+32)

    // A staging map: chunk c = t + 256*i -> row=c>>3, kc=c&7
    int a_row[4], a_kc[4], a_base[4];
#pragma unroll
    for (int i = 0; i < 4; i++) {
        const int c = t + 256 * i;
        const int row = c >> 3, kc = c & 7, m = kc & 3, s = kc >> 2;
        const int q1 = (m & 1) * 16 + (m & 2) * 2;  // 0,16,4,20
        a_row[i] = row; a_kc[i] = kc;
        a_base[i] = row * LDK + s * 32 + q1;
    }

    f32x4 acc[4][2];
#pragma unroll
    for (int i = 0; i < 4; i++)
#pragma unroll
        for (int j = 0; j < 2; j++) acc[i][j] = (f32x4){0.f, 0.f, 0.f, 0.f};

    uint4 apr[4];
    float4 wa0, wb0, wa1, wb1;

    auto loadA = [&](int k0) {
#pragma unroll
        for (int i = 0; i < 4; i++)
            apr[i] = *reinterpret_cast<const uint4*>(&xb[(size_t)a_row[i] * D_DIM + k0 + a_kc[i] * 8]);
    };
    auto loadW = [&](int k0) {
        const float4 z = make_float4(0.f, 0.f, 0.f, 0.f);
        const float* p0 = W + (size_t)(k0 + kk) * GEN_VV + nb + nn;
        const float* p1 = W + (size_t)(k0 + kk + 32) * GEN_VV + nb + nn;
        wa0 = wval ? *reinterpret_cast<const float4*>(p0) : z;
        wb0 = wval ? *reinterpret_cast<const float4*>(p0 + GEN_VV) : z;
        wa1 = wval ? *reinterpret_cast<const float4*>(p1) : z;
        wb1 = wval ? *reinterpret_cast<const float4*>(p1 + GEN_VV) : z;
    };

    loadA(0); loadW(0);

    for (int step = 0; step < 16; ++step) {
        // ---- write staged regs to LDS ----
#pragma unroll
        for (int i = 0; i < 4; i++) {
            union { uint4 u; bf16x8 v; } cv; cv.u = apr[i];
            *reinterpret_cast<bf16x4*>(&As[a_base[i]]) =
                __builtin_shufflevector(cv.v, cv.v, 0, 1, 2, 3);
            *reinterpret_cast<bf16x4*>(&As[a_base[i] + 8]) =
                __builtin_shufflevector(cv.v, cv.v, 4, 5, 6, 7);
        }
        {
            const float f0[4] = {wa0.x, wa0.y, wa0.z, wa0.w};
            const float g0[4] = {wb0.x, wb0.y, wb0.z, wb0.w};
            const float f1[4] = {wa1.x, wa1.y, wa1.z, wa1.w};
            const float g1[4] = {wb1.x, wb1.y, wb1.z, wb1.w};
#pragma unroll
            for (int j = 0; j < 4; j++) {
                bf16x2 p; p[0] = (__bf16)f0[j]; p[1] = (__bf16)g0[j];
                *reinterpret_cast<bf16x2*>(&Ws[(nn + j) * LDK + pos0]) = p;
                bf16x2 q; q[0] = (__bf16)f1[j]; q[1] = (__bf16)g1[j];
                *reinterpret_cast<bf16x2*>(&Ws[(nn + j) * LDK + pos1]) = q;
            }
        }
        __syncthreads();
        // ---- prefetch next tile (latency hides under MFMA phase) ----
        if (step < 15) { loadA((step + 1) * 64); loadW((step + 1) * 64); }
        // ---- compute ----
#pragma unroll
        for (int s = 0; s < 2; s++) {
            bf16x8 af[4], bfr[2];
#pragma unroll
            for (int fr = 0; fr < 4; fr++)
                af[fr] = *reinterpret_cast<const bf16x8*>(
                    &As[(wr * 64 + fr * 16 + r16) * LDK + s * 32 + g * 8]);
#pragma unroll
            for (int fc = 0; fc < 2; fc++)
                bfr[fc] = *reinterpret_cast<const bf16x8*>(
                    &Ws[(wc * 32 + fc * 16 + r16) * LDK + s * 32 + g * 8]);
#pragma unroll
            for (int fr = 0; fr < 4; fr++)
#pragma unroll
                for (int fc = 0; fc < 2; fc++)
                    acc[fr][fc] = __builtin_amdgcn_mfma_f32_16x16x32_bf16(af[fr], bfr[fc], acc[fr][fc], 0, 0, 0);
        }
        __syncthreads();
    }

#pragma unroll
    for (int fc = 0; fc < 2; fc++) {
        const int col = nb + wc * 32 + fc * 16 + r16;
        if (col < GEN_VV) {
            const float bg = bgen[col];
#pragma unroll
            for (int fr = 0; fr < 4; fr++) {
                const int row0 = wr * 64 + fr * 16 + g * 4;
#pragma unroll
                for (int j = 0; j < 4; j++)
                    logits[(size_t)(row0 + j) * GEN_VV + col] = acc[fr][fc][j] + bg;
            }
        }
    }
}

// ---------------- K3: per-half-row max and sum(exp) (256 blocks) ----------------
__global__ __launch_bounds__(256) void k_stats(const float* __restrict__ logits,
        float2* __restrict__ stats2) {
    __shared__ float red[4];
    __shared__ float bc;
    const int bi = blockIdx.x, b = bi >> 1, h = bi & 1, t = threadIdx.x;
    const float4* row = reinterpret_cast<const float4*>(logits + (size_t)b * GEN_VV) + h * 6250;
    float m = -1e30f;
    for (int i = t; i < 6250; i += 256) {
        float4 v = row[i];
        m = fmaxf(m, fmaxf(fmaxf(v.x, v.y), fmaxf(v.z, v.w)));
    }
#pragma unroll
    for (int d = 32; d >= 1; d >>= 1) m = fmaxf(m, __shfl_xor(m, d));
    if ((t & 63) == 0) red[t >> 6] = m;
    __syncthreads();
    if (t == 0) bc = fmaxf(fmaxf(red[0], red[1]), fmaxf(red[2], red[3]));
    __syncthreads();
    const float M = bc;
    float s = 0.f;
    for (int i = t; i < 6250; i += 256) {
        float4 v = row[i];
        s += __expf(v.x - M) + __expf(v.y - M) + __expf(v.z - M) + __expf(v.w - M);
    }
#pragma unroll
    for (int d = 32; d >= 1; d >>= 1) s += __shfl_xor(s, d);
    if ((t & 63) == 0) red[t >> 6] = s;
    __syncthreads();
    if (t == 0) stats2[bi] = make_float2(M, red[0] + red[1] + red[2] + red[3]);
}

// ---------------- K4: transpose tile + fused atomic scatter into out ----------------
__global__ __launch_bounds__(256) void k_probs_scatter(const float* __restrict__ logits,
        const float2* __restrict__ stats2, const float* __restrict__ interp,
        const int* __restrict__ g2o, float* __restrict__ out) {
    __shared__ float tile[32][33];
    const int v0 = blockIdx.x * 32, b0 = blockIdx.y * 32;
    const int t = threadIdx.x, tv = t & 31, p = t >> 5;
#pragma unroll
    for (int q = 0; q < 4; q++) {
        const int b = b0 + p + 8 * q;
        const float2 s0 = stats2[2 * b], s1 = stats2[2 * b + 1];
        const float M = fmaxf(s0.x, s1.x);
        const float denom = s0.y * __expf(s0.x - M) + s1.y * __expf(s1.x - M);
        const float sc = interp[b] / denom;
        const int v = v0 + tv;
        float val = 0.f;
        if (v < GEN_VV) val = __expf(logits[(size_t)b * GEN_VV + v] - M) * sc;
        tile[tv][p + 8 * q] = val;
    }
    __syncthreads();
    const int vi = t >> 3, bj = t & 7;
    const int v = v0 + vi;
    if (v < GEN_VV) {
        const int o = g2o[v];
#pragma unroll
        for (int j = 0; j < 4; j++) {
            const int b = b0 + bj * 4 + j;
            atomicAdd(&out[(size_t)b * OUT_VV + o], tile[vi][bj * 4 + j]);
        }
    }
}

// ---------------- K5: pointer scatter (atomics) ----------------
__global__ __launch_bounds__(256) void k_ptr(const float* __restrict__ alphas,
        const int* __restrict__ ctx, const int* __restrict__ i2o,
        const float* __restrict__ interp, float* __restrict__ out) {
    const int i = blockIdx.x * 256 + threadIdx.x;  // 65536 total
    const int b = i >> 9;
    const int o = i2o[ctx[i]];
    atomicAdd(&out[(size_t)b * OUT_VV + o], (1.0f - interp[b]) * alphas[i]);
}

extern "C" void kernel_launch(void* const* d_in, const int* in_sizes, int n_in,
                              void* d_out, int out_size, void* d_ws, size_t ws_size,
                              hipStream_t stream) {
    const float* x      = (const float*)d_in[0];
    const float* alphas = (const float*)d_in[1];
    const float* Wgate  = (const float*)d_in[2];
    const float* bgate  = (const float*)d_in[3];
    const float* Wgen   = (const float*)d_in[4];
    const float* bgen   = (const float*)d_in[5];
    const int*   ctx    = (const int*)d_in[6];
    const int*   g2o    = (const int*)d_in[7];
    const int*   i2o    = (const int*)d_in[8];
    float* out = (float*)d_out;

    // workspace: logits (25.6 MB) + xb (256 KB) + interp + stats2
    char* w = (char*)d_ws;
    float* logits = (float*)w;      w += (size_t)B_DIM * GEN_VV * 4;
    __bf16* xb = (__bf16*)w;        w += (size_t)B_DIM * D_DIM * 2;
    float* interp = (float*)w;      w += 512;
    float2* stats2 = (float2*)w;    w += 2048;

    hipMemsetAsync(d_out, 0, (size_t)B_DIM * OUT_VV * sizeof(float), stream);

    k_gate<<<B_DIM, 256, 0, stream>>>(x, Wgate, bgate, xb, interp);
    k_gemm<<<(GEN_VV + 63) / 64, 256, 0, stream>>>(xb, Wgen, bgen, logits);
    k_stats<<<2 * B_DIM, 256, 0, stream>>>(logits, stats2);
    k_probs_scatter<<<dim3((GEN_VV + 31) / 32, B_DIM / 32), 256, 0, stream>>>(
        logits, stats2, interp, g2o, out);
    k_ptr<<<(B_DIM * S_DIM) / 256, 256, 0, stream>>>(alphas, ctx, i2o, interp, out);
}

// Round 5
// 456.455 us; speedup vs baseline: 1.5299x; 1.5299x over previous
//
#include <hip/hip_runtime.h>
#include <hip/hip_bf16.h>
#include <stdint.h>

#define B_DIM 128
#define S_DIM 512
#define D_DIM 1024
#define GEN_VV 50000
#define GEN_PAD 50048
#define OUT_VV 50257
#define CAP 16
#define NSTAT 196

typedef float f32x4 __attribute__((ext_vector_type(4)));
typedef __bf16 bf16x8 __attribute__((ext_vector_type(8)));
typedef __bf16 bf16x4 __attribute__((ext_vector_type(4)));

typedef __attribute__((address_space(3))) void* lds_vp;
typedef const __attribute__((address_space(1))) void* glb_vp;

__device__ __forceinline__ void gload16(const void* g, void* l) {
    __builtin_amdgcn_global_load_lds((glb_vp)g, (lds_vp)l, 16, 0, 0);
}

// ---------------- K1: gate + x -> bf16 ----------------
__global__ __launch_bounds__(256) void k_gate(const float* __restrict__ x,
        const float* __restrict__ Wg, const float* __restrict__ bgate,
        __bf16* __restrict__ xb, float* __restrict__ interp) {
    __shared__ float red[4];
    const int b = blockIdx.x, t = threadIdx.x;
    float4 xv = reinterpret_cast<const float4*>(x + (size_t)b * D_DIM)[t];
    float4 wv = reinterpret_cast<const float4*>(Wg)[t];
    float dot = xv.x * wv.x + xv.y * wv.y + xv.z * wv.z + xv.w * wv.w;
    bf16x4 hb;
    hb[0] = (__bf16)xv.x; hb[1] = (__bf16)xv.y; hb[2] = (__bf16)xv.z; hb[3] = (__bf16)xv.w;
    reinterpret_cast<bf16x4*>(xb + (size_t)b * D_DIM)[t] = hb;
#pragma unroll
    for (int m = 32; m >= 1; m >>= 1) dot += __shfl_xor(dot, m);
    if ((t & 63) == 0) red[t >> 6] = dot;
    __syncthreads();
    if (t == 0) {
        float d = red[0] + red[1] + red[2] + red[3] + bgate[0];
        interp[b] = 1.0f / (1.0f + __expf(-d));
    }
}

// ---------------- K2: W [k][n] f32 -> Wt [n][k] bf16 (64x64 tiles) ----------------
__global__ __launch_bounds__(256) void k_wt(const float* __restrict__ W,
        __bf16* __restrict__ Wt) {
    __shared__ __bf16 tile[64][72];
    const int t = threadIdx.x;
    const int n0 = blockIdx.x * 64, k0 = blockIdx.y * 64;
    const int kk = t >> 4, n4 = (t & 15) * 4;
    const bool val = (n0 + n4 + 3) < GEN_VV;
#pragma unroll
    for (int p = 0; p < 4; p++) {
        const int k = p * 16 + kk;
        float4 v = val ? *reinterpret_cast<const float4*>(&W[(size_t)(k0 + k) * GEN_VV + n0 + n4])
                       : make_float4(0.f, 0.f, 0.f, 0.f);
        tile[n4 + 0][k] = (__bf16)v.x;
        tile[n4 + 1][k] = (__bf16)v.y;
        tile[n4 + 2][k] = (__bf16)v.z;
        tile[n4 + 3][k] = (__bf16)v.w;
    }
    __syncthreads();
#pragma unroll
    for (int p = 0; p < 2; p++) {
        const int n = p * 32 + (t >> 3), ks = (t & 7) * 8;
        *reinterpret_cast<uint4*>(&Wt[(size_t)(n0 + n) * D_DIM + k0 + ks]) =
            *reinterpret_cast<const uint4*>(&tile[n][ks]);
    }
}

// ---------------- K3: GEMM PT[v][b] = (xb @ Wt^T)^T + bgen ----------------
// BM=128, BN=64, BK=64, 4 waves 2x2. global_load_lds (16B) into swizzled-linear
// LDS (src pre-swizzled, read XOR-swizzled: both-sides involution).
__global__ __launch_bounds__(256) void k_gemm(const __bf16* __restrict__ xb,
        const __bf16* __restrict__ Wt, const float* __restrict__ bgen,
        float* __restrict__ PT) {
    __shared__ __align__(16) char smem[49152];
    __bf16* As = (__bf16*)smem;            // [2][128*64] bf16 = 2x16KB
    __bf16* Ws = (__bf16*)(smem + 32768);  // [2][64*64]  bf16 = 2x8KB
    float* tile = (float*)smem;            // epilogue alias: [64][133] f32

    const int t = threadIdx.x;
    const int lane = t & 63, wv = t >> 6;
    const int wr = wv >> 1, wc = wv & 1;
    const int g = lane >> 4, r16 = lane & 15;

    // bijective XCD swizzle (nwg=782)
    int bid = blockIdx.x;
    {
        const int nwg = 782, q = nwg / 8, r = nwg % 8;
        const int xcd = bid % 8, pos = bid / 8;
        bid = (xcd < r ? xcd * (q + 1) : r * (q + 1) + (xcd - r) * q) + pos;
    }
    const int nb = bid * 64;

    const int lrow = lane >> 3;                 // 0..7 (row within 8-row issue)
    const int lk = ((lane & 7) ^ lrow) * 8;     // pre-swizzled src k-elem offset

    f32x4 acc[4][2];
#pragma unroll
    for (int i = 0; i < 4; i++)
#pragma unroll
        for (int j = 0; j < 2; j++) acc[i][j] = (f32x4){0.f, 0.f, 0.f, 0.f};

    auto stage = [&](int buf, int k0) {
#pragma unroll
        for (int i = 0; i < 4; i++) {           // A: 4 issues/wave (8 rows each)
            const int br = wv * 32 + i * 8;
            gload16(&xb[(size_t)(br + lrow) * D_DIM + k0 + lk],
                    As + buf * 8192 + br * 64);
        }
#pragma unroll
        for (int i = 0; i < 2; i++) {           // W: 2 issues/wave
            const int br = wv * 16 + i * 8;
            gload16(&Wt[(size_t)(nb + br + lrow) * D_DIM + k0 + lk],
                    Ws + buf * 4096 + br * 64);
        }
    };

    stage(0, 0);
    __syncthreads();   // drains vmcnt before first compute

    for (int step = 0; step < 16; ++step) {
        const int buf = step & 1;
        if (step < 15) stage(buf ^ 1, (step + 1) * 64);
        const __bf16* A = As + buf * 8192;
        const __bf16* Wb = Ws + buf * 4096;
#pragma unroll
        for (int s = 0; s < 2; s++) {
            bf16x8 af[4], bfr[2];
#pragma unroll
            for (int fr = 0; fr < 4; fr++) {
                const int row = wr * 64 + fr * 16 + r16;
                const int c = ((s * 4 + g) ^ (row & 7)) * 8;
                af[fr] = *reinterpret_cast<const bf16x8*>(&A[row * 64 + c]);
            }
#pragma unroll
            for (int fc = 0; fc < 2; fc++) {
                const int row = wc * 32 + fc * 16 + r16;
                const int c = ((s * 4 + g) ^ (row & 7)) * 8;
                bfr[fc] = *reinterpret_cast<const bf16x8*>(&Wb[row * 64 + c]);
            }
#pragma unroll
            for (int fr = 0; fr < 4; fr++)
#pragma unroll
                for (int fc = 0; fc < 2; fc++)
                    acc[fr][fc] = __builtin_amdgcn_mfma_f32_16x16x32_bf16(
                        af[fr], bfr[fc], acc[fr][fc], 0, 0, 0);
        }
        __syncthreads();   // drains prefetch vmcnt + lgkm for all waves
    }

    // epilogue: acc -> LDS tile[v][b] (stride 133, 2-way max conflict) -> PT
#pragma unroll
    for (int fc = 0; fc < 2; fc++) {
        const int v = wc * 32 + fc * 16 + r16;
        const int col = nb + v;
        const float bg = (col < GEN_VV) ? bgen[col] : 0.f;
#pragma unroll
        for (int fr = 0; fr < 4; fr++) {
            const int b = wr * 64 + fr * 16 + g * 4;
#pragma unroll
            for (int j = 0; j < 4; j++)
                tile[v * 133 + b + j] = acc[fr][fc][j] + bg;
        }
    }
    __syncthreads();
    {
        const int r = t >> 2, seg = t & 3;
        if (nb + r < GEN_VV) {
#pragma unroll
            for (int p = 0; p < 8; p++) {
                const int c4 = seg * 4 + p * 16;
                float4 o;
                o.x = tile[r * 133 + c4 + 0];
                o.y = tile[r * 133 + c4 + 1];
                o.z = tile[r * 133 + c4 + 2];
                o.w = tile[r * 133 + c4 + 3];
                *reinterpret_cast<float4*>(&PT[(size_t)(nb + r) * B_DIM + c4]) = o;
            }
        }
    }
}

// ---------------- K4: online (max, sumexp) per b over PT v-chunks ----------------
__global__ __launch_bounds__(256) void k_statsT(const float* __restrict__ PT,
        float2* __restrict__ partials) {
    __shared__ float4 red[256];
    const int t = threadIdx.x, lane = t & 63, wvv = t >> 6;
    const int v0 = blockIdx.x * 256;
    float m0 = -3.0e38f, m1 = -3.0e38f, s0 = 0.f, s1 = 0.f;
    for (int i = 0; i < 64; i++) {
        const int v = v0 + wvv * 64 + i;
        if (v < GEN_VV) {
            float2 x = *reinterpret_cast<const float2*>(&PT[(size_t)v * B_DIM + lane * 2]);
            float nm0 = fmaxf(m0, x.x), nm1 = fmaxf(m1, x.y);
            s0 = s0 * __expf(m0 - nm0) + __expf(x.x - nm0);
            s1 = s1 * __expf(m1 - nm1) + __expf(x.y - nm1);
            m0 = nm0; m1 = nm1;
        }
    }
    red[t] = make_float4(m0, s0, m1, s1);
    __syncthreads();
    if (t < 64) {
        float4 a = red[t], b = red[t + 64], c = red[t + 128], d = red[t + 192];
        float M0 = fmaxf(fmaxf(a.x, b.x), fmaxf(c.x, d.x));
        float S0 = a.y * __expf(a.x - M0) + b.y * __expf(b.x - M0) +
                   c.y * __expf(c.x - M0) + d.y * __expf(d.x - M0);
        float M1 = fmaxf(fmaxf(a.z, b.z), fmaxf(c.z, d.z));
        float S1 = a.w * __expf(a.z - M1) + b.w * __expf(b.z - M1) +
                   c.w * __expf(c.z - M1) + d.w * __expf(d.z - M1);
        partials[blockIdx.x * B_DIM + 2 * t] = make_float2(M0, S0);
        partials[blockIdx.x * B_DIM + 2 * t + 1] = make_float2(M1, S1);
    }
}

__global__ __launch_bounds__(128) void k_statsC(const float2* __restrict__ partials,
        const float* __restrict__ interp, float* __restrict__ Mv,
        float* __restrict__ scv) {
    const int b = threadIdx.x;
    float M = -3.0e38f;
    for (int i = 0; i < NSTAT; i++) M = fmaxf(M, partials[i * B_DIM + b].x);
    float S = 0.f;
    for (int i = 0; i < NSTAT; i++) {
        float2 p = partials[i * B_DIM + b];
        S += p.y * __expf(p.x - M);
    }
    Mv[b] = M;
    scv[b] = interp[b] / S;
}

// ---------------- K5: fixed-capacity bucket build ----------------
__global__ __launch_bounds__(256) void k_scatter(const int* __restrict__ g2o,
        int* __restrict__ count, int* __restrict__ items) {
    const int v = blockIdx.x * 256 + threadIdx.x;
    if (v < GEN_VV) {
        const int o = g2o[v];
        const int slot = atomicAdd(&count[o], 1);
        if (slot < CAP) items[o * CAP + slot] = v;
    }
}

// ---------------- K6: gather buckets -> out (full overwrite) ----------------
__global__ __launch_bounds__(256) void k_gather(const float* __restrict__ PT,
        const int* __restrict__ count, const int* __restrict__ items,
        const float* __restrict__ Mv, const float* __restrict__ scv,
        float* __restrict__ out) {
    __shared__ float tile[64 * 133];
    const int t = threadIdx.x;
    const int o0 = blockIdx.x * 64;
    const int oi = t & 63, bseg = t >> 6;   // each thread: one o, 32 b's
    const int o = o0 + oi;
    float4 M[8], SC[8];
#pragma unroll
    for (int i = 0; i < 8; i++) {
        M[i] = *reinterpret_cast<const float4*>(&Mv[bseg * 32 + i * 4]);
        SC[i] = *reinterpret_cast<const float4*>(&scv[bseg * 32 + i * 4]);
    }
    f32x4 acc[8];
#pragma unroll
    for (int i = 0; i < 8; i++) acc[i] = (f32x4){0.f, 0.f, 0.f, 0.f};
    if (o < OUT_VV) {
        int c = count[o]; c = c < CAP ? c : CAP;
        for (int s = 0; s < c; s++) {
            const int v = items[o * CAP + s];
            const float* row = &PT[(size_t)v * B_DIM + bseg * 32];
#pragma unroll
            for (int i = 0; i < 8; i++) {
                float4 x = *reinterpret_cast<const float4*>(&row[i * 4]);
                acc[i][0] += __expf(x.x - M[i].x) * SC[i].x;
                acc[i][1] += __expf(x.y - M[i].y) * SC[i].y;
                acc[i][2] += __expf(x.z - M[i].z) * SC[i].z;
                acc[i][3] += __expf(x.w - M[i].w) * SC[i].w;
            }
        }
    }
#pragma unroll
    for (int i = 0; i < 8; i++)
#pragma unroll
        for (int j = 0; j < 4; j++)
            tile[oi * 133 + bseg * 32 + i * 4 + j] = acc[i][j];
    __syncthreads();
    const int oo = t & 63, br = t >> 6;
    if (o0 + oo < OUT_VV) {
        for (int p = 0; p < 32; p++) {
            const int b = p * 4 + br;
            out[(size_t)b * OUT_VV + o0 + oo] = tile[oo * 133 + b];
        }
    }
}

// ---------------- K7: pointer scatter (atomics, 65K only) ----------------
__global__ __launch_bounds__(256) void k_ptr(const float* __restrict__ alphas,
        const int* __restrict__ ctx, const int* __restrict__ i2o,
        const float* __restrict__ interp, float* __restrict__ out) {
    const int i = blockIdx.x * 256 + threadIdx.x;
    const int b = i >> 9;
    const int o = i2o[ctx[i]];
    atomicAdd(&out[(size_t)b * OUT_VV + o], (1.0f - interp[b]) * alphas[i]);
}

extern "C" void kernel_launch(void* const* d_in, const int* in_sizes, int n_in,
                              void* d_out, int out_size, void* d_ws, size_t ws_size,
                              hipStream_t stream) {
    const float* x      = (const float*)d_in[0];
    const float* alphas = (const float*)d_in[1];
    const float* Wgate  = (const float*)d_in[2];
    const float* bgate  = (const float*)d_in[3];
    const float* Wgen   = (const float*)d_in[4];
    const float* bgen   = (const float*)d_in[5];
    const int*   ctx    = (const int*)d_in[6];
    const int*   g2o    = (const int*)d_in[7];
    const int*   i2o    = (const int*)d_in[8];
    float* out = (float*)d_out;

    // workspace (~132 MB)
    char* w = (char*)d_ws;
    __bf16* Wt = (__bf16*)w;       w += (size_t)GEN_PAD * D_DIM * 2;   // 102.5 MB
    float* PT = (float*)w;         w += (size_t)GEN_VV * B_DIM * 4;    // 25.6 MB
    __bf16* xb = (__bf16*)w;       w += (size_t)B_DIM * D_DIM * 2;
    float* interp = (float*)w;     w += 512;
    float* Mv = (float*)w;         w += 512;
    float* scv = (float*)w;        w += 512;
    float2* partials = (float2*)w; w += (size_t)NSTAT * B_DIM * 8;
    int* count = (int*)w;          w += ((size_t)OUT_VV * 4 + 255) & ~(size_t)255;
    int* items = (int*)w;          w += (size_t)OUT_VV * CAP * 4;

    hipMemsetAsync(count, 0, (size_t)OUT_VV * sizeof(int), stream);

    k_gate<<<B_DIM, 256, 0, stream>>>(x, Wgate, bgate, xb, interp);
    k_wt<<<dim3(782, 16), 256, 0, stream>>>(Wgen, Wt);
    k_gemm<<<782, 256, 0, stream>>>(xb, Wt, bgen, PT);
    k_statsT<<<NSTAT, 256, 0, stream>>>(PT, partials);
    k_statsC<<<1, 128, 0, stream>>>(partials, interp, Mv, scv);
    k_scatter<<<(GEN_VV + 255) / 256, 256, 0, stream>>>(g2o, count, items);
    k_gather<<<(OUT_VV + 63) / 64, 256, 0, stream>>>(PT, count, items, Mv, scv, out);
    k_ptr<<<(B_DIM * S_DIM) / 256, 256, 0, stream>>>(alphas, ctx, i2o, interp, out);
}

// Round 6
// 437.209 us; speedup vs baseline: 1.5972x; 1.0440x over previous
//
#include <hip/hip_runtime.h>
#include <hip/hip_bf16.h>
#include <stdint.h>

#define B_DIM 128
#define S_DIM 512
#define D_DIM 1024
#define GEN_VV 50000
#define OUT_VV 50257
#define CAP 16

typedef float f32x4 __attribute__((ext_vector_type(4)));
typedef __bf16 bf16x8 __attribute__((ext_vector_type(8)));
typedef __bf16 bf16x4 __attribute__((ext_vector_type(4)));
typedef __bf16 bf16x2 __attribute__((ext_vector_type(2)));

typedef __attribute__((address_space(3))) void* lds_vp;
typedef const __attribute__((address_space(1))) void* glb_vp;

__device__ __forceinline__ void gload16(const void* g, void* l) {
    __builtin_amdgcn_global_load_lds((glb_vp)g, (lds_vp)l, 16, 0, 0);
}

// ---------------- K1: gate + x -> bf16 ----------------
__global__ __launch_bounds__(256) void k_gate(const float* __restrict__ x,
        const float* __restrict__ Wg, const float* __restrict__ bgate,
        __bf16* __restrict__ xb, float* __restrict__ interp) {
    __shared__ float red[4];
    const int b = blockIdx.x, t = threadIdx.x;
    float4 xv = reinterpret_cast<const float4*>(x + (size_t)b * D_DIM)[t];
    float4 wv = reinterpret_cast<const float4*>(Wg)[t];
    float dot = xv.x * wv.x + xv.y * wv.y + xv.z * wv.z + xv.w * wv.w;
    bf16x4 hb;
    hb[0] = (__bf16)xv.x; hb[1] = (__bf16)xv.y; hb[2] = (__bf16)xv.z; hb[3] = (__bf16)xv.w;
    reinterpret_cast<bf16x4*>(xb + (size_t)b * D_DIM)[t] = hb;
#pragma unroll
    for (int m = 32; m >= 1; m >>= 1) dot += __shfl_xor(dot, m);
    if ((t & 63) == 0) red[t >> 6] = dot;
    __syncthreads();
    if (t == 0) {
        float d = red[0] + red[1] + red[2] + red[3] + bgate[0];
        interp[b] = 1.0f / (1.0f + __expf(-d));
    }
}

// ---------------- K2: fused GEMM + exp + denominator ----------------
// BM=128(all b), BN=256, BK=32, 4 waves (each: 128b x 64n).
// A: bf16 via global_load_lds, linear [row][32].
// W: fp32 256B/row-coalesced reg-stage -> cast bf16 -> LDS [n][32] with
//    k-block XOR swizzle (slot = cb ^ (n>>2 & 3)): write 4-way, read conflict-free.
// Epilogue: e = exp(logit + bgen) -> PT[v][b]; S[b] += column sums (shfl tree + atomics).
__global__ __launch_bounds__(256, 2) void k_gemm(const __bf16* __restrict__ xb,
        const float* __restrict__ W, const float* __restrict__ bgen,
        float* __restrict__ PT, float* __restrict__ S) {
    __shared__ __align__(16) char smem[49152];
    __bf16* As = (__bf16*)smem;            // 2 bufs x 4096 elems (128x32)
    __bf16* Ws = (__bf16*)(smem + 16384);  // 2 bufs x 8192 elems (256x32)

    const int t = threadIdx.x;
    const int lane = t & 63, wv = t >> 6;
    const int g = lane >> 4, r16 = lane & 15;
    const int nb = blockIdx.x * 256;

    // W staging map: q = n-group (4 n's), uk = k-pair base
    const int q = t >> 2, uk = t & 3;
    const int nn = q * 4;
    const bool wval = (nb + nn + 3) < GEN_VV;

    float4 wreg[8];
    auto wload = [&](int k0) {
        const float4 z = make_float4(0.f, 0.f, 0.f, 0.f);
#pragma unroll
        for (int i = 0; i < 4; i++) {
            const float* p = W + (size_t)(k0 + 2 * (uk + 4 * i)) * GEN_VV + nb + nn;
            wreg[2 * i]     = wval ? *reinterpret_cast<const float4*>(p) : z;
            wreg[2 * i + 1] = wval ? *reinterpret_cast<const float4*>(p + GEN_VV) : z;
        }
    };
    auto stageW = [&](int buf) {
#pragma unroll
        for (int i = 0; i < 4; i++) {
            const float lo[4] = {wreg[2*i].x, wreg[2*i].y, wreg[2*i].z, wreg[2*i].w};
            const float hi[4] = {wreg[2*i+1].x, wreg[2*i+1].y, wreg[2*i+1].z, wreg[2*i+1].w};
            const int slot = (i ^ (q & 3)) * 8 + 2 * uk;
#pragma unroll
            for (int j = 0; j < 4; j++) {
                bf16x2 pr; pr[0] = (__bf16)lo[j]; pr[1] = (__bf16)hi[j];
                *reinterpret_cast<bf16x2*>(&Ws[buf * 8192 + (nn + j) * 32 + slot]) = pr;
            }
        }
    };
    auto gloadA = [&](int buf, int k0) {
#pragma unroll
        for (int j2 = 0; j2 < 2; j2++) {
            const int rowbase = wv * 32 + j2 * 16;
            gload16(&xb[(size_t)(rowbase + (lane >> 2)) * D_DIM + k0 + (lane & 3) * 8],
                    As + buf * 4096 + rowbase * 32);
        }
    };

    f32x4 acc[8][4];
#pragma unroll
    for (int i = 0; i < 8; i++)
#pragma unroll
        for (int j = 0; j < 4; j++) acc[i][j] = (f32x4){0.f, 0.f, 0.f, 0.f};

    // prologue
    wload(0);
    stageW(0);
    gloadA(0, 0);
    wload(32);
    __syncthreads();

    const int sl = (g ^ (r16 >> 2)) * 8;
    for (int st = 0; st < 32; ++st) {
        const int cur = st & 1;
        if (st < 31) { gloadA(cur ^ 1, (st + 1) * 32); stageW(cur ^ 1); }
        if (st < 30) wload((st + 2) * 32);
        bf16x8 af[8], bfr[4];
#pragma unroll
        for (int fr = 0; fr < 8; fr++)
            af[fr] = *reinterpret_cast<const bf16x8*>(&As[cur * 4096 + (fr * 16 + r16) * 32 + g * 8]);
#pragma unroll
        for (int fc = 0; fc < 4; fc++)
            bfr[fc] = *reinterpret_cast<const bf16x8*>(
                &Ws[cur * 8192 + (wv * 64 + fc * 16 + r16) * 32 + sl]);
#pragma unroll
        for (int fr = 0; fr < 8; fr++)
#pragma unroll
            for (int fc = 0; fc < 4; fc++)
                acc[fr][fc] = __builtin_amdgcn_mfma_f32_16x16x32_bf16(af[fr], bfr[fc], acc[fr][fc], 0, 0, 0);
        __syncthreads();
    }

    // epilogue: exp, PT write, per-b denominator partials
    f32x4 ps[8];
#pragma unroll
    for (int fr = 0; fr < 8; fr++) ps[fr] = (f32x4){0.f, 0.f, 0.f, 0.f};
#pragma unroll
    for (int fc = 0; fc < 4; fc++) {
        const int v = nb + wv * 64 + fc * 16 + r16;
        const bool vv = v < GEN_VV;
        const float bg = vv ? bgen[v] : 0.f;
#pragma unroll
        for (int fr = 0; fr < 8; fr++) {
            f32x4 ev;
#pragma unroll
            for (int j = 0; j < 4; j++)
                ev[j] = vv ? __expf(acc[fr][fc][j] + bg) : 0.f;
            if (vv) {
                float4 o; o.x = ev[0]; o.y = ev[1]; o.z = ev[2]; o.w = ev[3];
                *reinterpret_cast<float4*>(&PT[(size_t)v * B_DIM + fr * 16 + g * 4]) = o;
            }
            ps[fr] += ev;
        }
    }
#pragma unroll
    for (int fr = 0; fr < 8; fr++) {
#pragma unroll
        for (int j = 0; j < 4; j++) {
            float s = ps[fr][j];
            s += __shfl_xor(s, 1);
            s += __shfl_xor(s, 2);
            s += __shfl_xor(s, 4);
            s += __shfl_xor(s, 8);
            if (r16 == 0) atomicAdd(&S[fr * 16 + g * 4 + j], s);
        }
    }
}

// ---------------- K3: scv = interp / S ----------------
__global__ __launch_bounds__(128) void k_scale(const float* __restrict__ S,
        const float* __restrict__ interp, float* __restrict__ scv) {
    const int b = threadIdx.x;
    scv[b] = interp[b] / S[b];
}

// ---------------- K4: fixed-capacity bucket build ----------------
__global__ __launch_bounds__(256) void k_scatter(const int* __restrict__ g2o,
        int* __restrict__ count, int* __restrict__ items) {
    const int v = blockIdx.x * 256 + threadIdx.x;
    if (v < GEN_VV) {
        const int o = g2o[v];
        const int slot = atomicAdd(&count[o], 1);
        if (slot < CAP) items[o * CAP + slot] = v;
    }
}

// ---------------- K5: gather buckets -> out (full overwrite) ----------------
__global__ __launch_bounds__(256) void k_gather(const float* __restrict__ PT,
        const int* __restrict__ count, const int* __restrict__ items,
        const float* __restrict__ scv, float* __restrict__ out) {
    __shared__ float tile[64 * 133];
    const int t = threadIdx.x;
    const int o0 = blockIdx.x * 64;
    const int oi = t & 63, bseg = t >> 6;   // thread: one o, 32 b's
    const int o = o0 + oi;
    float4 SC[8];
#pragma unroll
    for (int i = 0; i < 8; i++)
        SC[i] = *reinterpret_cast<const float4*>(&scv[bseg * 32 + i * 4]);
    f32x4 acc[8];
#pragma unroll
    for (int i = 0; i < 8; i++) acc[i] = (f32x4){0.f, 0.f, 0.f, 0.f};
    if (o < OUT_VV) {
        int c = count[o]; c = c < CAP ? c : CAP;
        for (int s = 0; s < c; s++) {
            const int v = items[o * CAP + s];
            const float* row = &PT[(size_t)v * B_DIM + bseg * 32];
#pragma unroll
            for (int i = 0; i < 8; i++) {
                float4 x = *reinterpret_cast<const float4*>(&row[i * 4]);
                acc[i][0] += x.x; acc[i][1] += x.y; acc[i][2] += x.z; acc[i][3] += x.w;
            }
        }
    }
#pragma unroll
    for (int i = 0; i < 8; i++) {
        tile[oi * 133 + bseg * 32 + i * 4 + 0] = acc[i][0] * SC[i].x;
        tile[oi * 133 + bseg * 32 + i * 4 + 1] = acc[i][1] * SC[i].y;
        tile[oi * 133 + bseg * 32 + i * 4 + 2] = acc[i][2] * SC[i].z;
        tile[oi * 133 + bseg * 32 + i * 4 + 3] = acc[i][3] * SC[i].w;
    }
    __syncthreads();
    const int oo = t & 63, br = t >> 6;
    if (o0 + oo < OUT_VV) {
        for (int p = 0; p < 32; p++) {
            const int b = p * 4 + br;
            out[(size_t)b * OUT_VV + o0 + oo] = tile[oo * 133 + b];
        }
    }
}

// ---------------- K6: pointer scatter (atomics, 65K only) ----------------
__global__ __launch_bounds__(256) void k_ptr(const float* __restrict__ alphas,
        const int* __restrict__ ctx, const int* __restrict__ i2o,
        const float* __restrict__ interp, float* __restrict__ out) {
    const int i = blockIdx.x * 256 + threadIdx.x;
    const int b = i >> 9;
    const int o = i2o[ctx[i]];
    atomicAdd(&out[(size_t)b * OUT_VV + o], (1.0f - interp[b]) * alphas[i]);
}

extern "C" void kernel_launch(void* const* d_in, const int* in_sizes, int n_in,
                              void* d_out, int out_size, void* d_ws, size_t ws_size,
                              hipStream_t stream) {
    const float* x      = (const float*)d_in[0];
    const float* alphas = (const float*)d_in[1];
    const float* Wgate  = (const float*)d_in[2];
    const float* bgate  = (const float*)d_in[3];
    const float* Wgen   = (const float*)d_in[4];
    const float* bgen   = (const float*)d_in[5];
    const int*   ctx    = (const int*)d_in[6];
    const int*   g2o    = (const int*)d_in[7];
    const int*   i2o    = (const int*)d_in[8];
    float* out = (float*)d_out;

    // workspace (~29 MB)
    char* w = (char*)d_ws;
    float* PT = (float*)w;         w += (size_t)GEN_VV * B_DIM * 4;    // 25.6 MB
    __bf16* xb = (__bf16*)w;       w += (size_t)B_DIM * D_DIM * 2;
    float* interp = (float*)w;     w += 512;
    float* scv = (float*)w;        w += 512;
    int* count = (int*)w;          w += ((size_t)OUT_VV * 4 + 511) & ~(size_t)511;
    float* S = (float*)w;          w += 512;
    int* items = (int*)w;          w += (size_t)OUT_VV * CAP * 4;

    hipMemsetAsync(count, 0, (size_t)OUT_VV * sizeof(int), stream);
    hipMemsetAsync(S, 0, B_DIM * sizeof(float), stream);

    k_gate<<<B_DIM, 256, 0, stream>>>(x, Wgate, bgate, xb, interp);
    k_gemm<<<(GEN_VV + 255) / 256, 256, 0, stream>>>(xb, Wgen, bgen, PT, S);
    k_scale<<<1, 128, 0, stream>>>(S, interp, scv);
    k_scatter<<<(GEN_VV + 255) / 256, 256, 0, stream>>>(g2o, count, items);
    k_gather<<<(OUT_VV + 63) / 64, 256, 0, stream>>>(PT, count, items, scv, out);
    k_ptr<<<(B_DIM * S_DIM) / 256, 256, 0, stream>>>(alphas, ctx, i2o, interp, out);
}